// Round 3
// baseline (1798.980 us; speedup 1.0000x reference)
//
#include <hip/hip_runtime.h>
#include <hip/hip_bf16.h>
#include <math.h>

typedef unsigned short u16;
typedef short v8s __attribute__((ext_vector_type(8)));
typedef float v4f __attribute__((ext_vector_type(4)));

#define SCALE_F 0.11180339887498949f

__device__ __forceinline__ float bf2f(u16 x) {
    unsigned int u = ((unsigned int)x) << 16;
    return __builtin_bit_cast(float, u);
}
__device__ __forceinline__ u16 f2bf(float f) {
    unsigned int u = __builtin_bit_cast(unsigned int, f);
    unsigned int r = (u + 0x7FFFu + ((u >> 16) & 1u)) >> 16;
    return (u16)r;
}
__device__ __forceinline__ float scrub(float v) {
    return (fabsf(v) < 1e30f) ? v : 0.f;   // NaN compares false -> 0
}
__device__ __forceinline__ v8s zero8() {
    union { v8s v; short s[8]; } t;
#pragma unroll
    for (int i = 0; i < 8; i++) t.s[i] = 0;
    return t.v;
}

// ---------------------------------------------------------------------------
// Split-precision GEMM (bf16x3, ~f32 accurate): C = A[M,K] @ B[K,N] + bias.
// A,B,bias f32. Requires M%64==0, N%64==0, K%32==0.
// outb: bf16 store; outf: f32 store; outSum: f32 atomic block-sum over
// 32-token groups, layout [(b<<5)+blk][N] (rows are tokens, b=row>>10).
// ---------------------------------------------------------------------------
__global__ __launch_bounds__(256) void gemmS_kernel(
    const float* __restrict__ A, const float* __restrict__ B,
    const float* __restrict__ bias, int M, int N, int K,
    u16* __restrict__ outb, float* __restrict__ outf, float* __restrict__ outSum)
{
    __shared__ __align__(16) u16 Ah[64][32], Al[64][32];
    __shared__ __align__(16) u16 Bh[64][32], Bl[64][32];   // [n][k]

    const int tid  = threadIdx.x;
    const int bm   = blockIdx.x * 64, bn = blockIdx.y * 64;
    const int w    = tid >> 6, lane = tid & 63;
    const int quad = lane >> 4, l = lane & 15;

    v4f acc[4];
#pragma unroll
    for (int nt = 0; nt < 4; nt++)
#pragma unroll
        for (int r = 0; r < 4; r++) acc[nt][r] = 0.f;

    const int ar = tid >> 2, ak = (tid & 3) * 8;   // A: 64 rows x 32 k
    const int kr = tid >> 3, nc = (tid & 7) * 8;   // B: 32 k x 64 n

    for (int k0 = 0; k0 < K; k0 += 32) {
        float4 a0 = *(const float4*)(A + (size_t)(bm + ar) * K + (k0 + ak));
        float4 a1 = *(const float4*)(A + (size_t)(bm + ar) * K + (k0 + ak) + 4);
        float4 b0 = *(const float4*)(B + (size_t)(k0 + kr) * N + (bn + nc));
        float4 b1 = *(const float4*)(B + (size_t)(k0 + kr) * N + (bn + nc) + 4);
        float av[8] = {a0.x,a0.y,a0.z,a0.w,a1.x,a1.y,a1.z,a1.w};
        float bv[8] = {b0.x,b0.y,b0.z,b0.w,b1.x,b1.y,b1.z,b1.w};
        __syncthreads();
#pragma unroll
        for (int j = 0; j < 8; j++) {
            u16 h = f2bf(av[j]);
            Ah[ar][ak + j] = h;
            Al[ar][ak + j] = f2bf(av[j] - bf2f(h));
            u16 g = f2bf(bv[j]);
            Bh[nc + j][kr] = g;
            Bl[nc + j][kr] = f2bf(bv[j] - bf2f(g));
        }
        __syncthreads();

        v8s ah = *(const v8s*)(&Ah[w * 16 + l][quad * 8]);
        v8s al = *(const v8s*)(&Al[w * 16 + l][quad * 8]);
#pragma unroll
        for (int nt = 0; nt < 4; nt++) {
            v8s bh = *(const v8s*)(&Bh[nt * 16 + l][quad * 8]);
            v8s bl = *(const v8s*)(&Bl[nt * 16 + l][quad * 8]);
            acc[nt] = __builtin_amdgcn_mfma_f32_16x16x32_bf16(ah, bh, acc[nt], 0, 0, 0);
            acc[nt] = __builtin_amdgcn_mfma_f32_16x16x32_bf16(ah, bl, acc[nt], 0, 0, 0);
            acc[nt] = __builtin_amdgcn_mfma_f32_16x16x32_bf16(al, bh, acc[nt], 0, 0, 0);
        }
    }

#pragma unroll
    for (int nt = 0; nt < 4; nt++) {
        int col = bn + nt * 16 + l;
        float bvs = bias[col];
#pragma unroll
        for (int r = 0; r < 4; r++) {
            int row = bm + w * 16 + quad * 4 + r;
            float c = scrub(acc[nt][r] + bvs);
            size_t off = (size_t)row * N + col;
            if (outf) outf[off] = c;
            if (outb) outb[off] = f2bf(c);
            if (outSum) {
                int bb = row >> 10, blk = (row & 1023) >> 5;
                atomicAdd(&outSum[(size_t)((bb << 5) + blk) * N + col], c);
            }
        }
    }
}

// ---------------------------------------------------------------------------
// Plain bf16 GEMM: C = act(A @ B + bias). B,bias f32; A f32 (aF32=1) or bf16.
// M%64==0, K%32==0, N arbitrary (masked). act==1 -> exact GELU.
// outT: bf16 transposed-V store [b*32+h][80][1024] (requires N=2560).
// ---------------------------------------------------------------------------
__global__ __launch_bounds__(256) void gemm_kernel(
    const void* __restrict__ Av, const float* __restrict__ B,
    const float* __restrict__ bias, int M, int N, int K, int act, int aF32,
    u16* __restrict__ outb, float* __restrict__ outf, u16* __restrict__ outT)
{
    __shared__ __align__(16) u16 As[64][32];
    __shared__ __align__(16) u16 Bs[64][32];   // [n][k]

    const int tid  = threadIdx.x;
    const int bm   = blockIdx.x * 64, bn = blockIdx.y * 64;
    const int w    = tid >> 6, lane = tid & 63;
    const int quad = lane >> 4, l = lane & 15;

    v4f acc[4];
#pragma unroll
    for (int nt = 0; nt < 4; nt++)
#pragma unroll
        for (int r = 0; r < 4; r++) acc[nt][r] = 0.f;

    const int ar = tid >> 2, ak = (tid & 3) * 8;
    const int kr = tid >> 3, nc = (tid & 7) * 8;

    for (int k0 = 0; k0 < K; k0 += 32) {
        u16 a8[8];
        if (aF32) {
            const float* Af = (const float*)Av;
            float4 a0 = *(const float4*)(Af + (size_t)(bm + ar) * K + (k0 + ak));
            float4 a1 = *(const float4*)(Af + (size_t)(bm + ar) * K + (k0 + ak) + 4);
            a8[0]=f2bf(a0.x); a8[1]=f2bf(a0.y); a8[2]=f2bf(a0.z); a8[3]=f2bf(a0.w);
            a8[4]=f2bf(a1.x); a8[5]=f2bf(a1.y); a8[6]=f2bf(a1.z); a8[7]=f2bf(a1.w);
        } else {
            *(uint4*)a8 = *(const uint4*)((const u16*)Av + (size_t)(bm + ar) * K + (k0 + ak));
        }
        u16 b8[8];
        const float* Bp = B + (size_t)(k0 + kr) * N + (bn + nc);
        if (bn + 64 <= N) {
            float4 b0 = *(const float4*)Bp;
            float4 b1 = *(const float4*)(Bp + 4);
            b8[0]=f2bf(b0.x); b8[1]=f2bf(b0.y); b8[2]=f2bf(b0.z); b8[3]=f2bf(b0.w);
            b8[4]=f2bf(b1.x); b8[5]=f2bf(b1.y); b8[6]=f2bf(b1.z); b8[7]=f2bf(b1.w);
        } else {
#pragma unroll
            for (int j = 0; j < 8; j++) {
                int cc = bn + nc + j;
                b8[j] = (cc < N) ? f2bf(Bp[j]) : (u16)0;
            }
        }
        __syncthreads();
        *(uint4*)(&As[ar][ak]) = *(uint4*)a8;
#pragma unroll
        for (int j = 0; j < 8; j++) Bs[nc + j][kr] = b8[j];
        __syncthreads();

        v8s af = *(const v8s*)(&As[w * 16 + l][quad * 8]);
#pragma unroll
        for (int nt = 0; nt < 4; nt++) {
            v8s bf = *(const v8s*)(&Bs[nt * 16 + l][quad * 8]);
            acc[nt] = __builtin_amdgcn_mfma_f32_16x16x32_bf16(af, bf, acc[nt], 0, 0, 0);
        }
    }

#pragma unroll
    for (int nt = 0; nt < 4; nt++) {
        int col = bn + nt * 16 + l;
        if (col < N) {
            float bvs = bias[col];
#pragma unroll
            for (int r = 0; r < 4; r++) {
                int row = bm + w * 16 + quad * 4 + r;
                float c = acc[nt][r] + bvs;
                if (act == 1) c = 0.5f * c * (1.0f + erff(c * 0.70710678118654752f));
                c = scrub(c);
                size_t off = (size_t)row * N + col;
                if (outf) outf[off] = c;
                if (outb) outb[off] = f2bf(c);
                if (outT) {
                    int bb = row >> 10, s = row & 1023;
                    int hh = col / 80, dd = col - hh * 80;
                    outT[(((size_t)((bb << 5) + hh) * 80) + dd) * 1024 + s] = f2bf(c);
                }
            }
        }
    }
}

// ---------------------------------------------------------------------------
// F[(b*1024+h*32+blk)][j*80+d] = V[b,blk*32+j,h*80+d] + pos, V from vt[bh][80][1024]
// ---------------------------------------------------------------------------
__global__ void gatherFT_kernel(const u16* __restrict__ vt, const float* __restrict__ pos,
                                u16* __restrict__ F)
{
    int row = blockIdx.y;
    int col = blockIdx.x * 256 + threadIdx.x;
    if (col >= 2560) return;
    int b = row >> 10, h = (row >> 5) & 31, blk = row & 31;
    int j = col / 80, d = col - j * 80;
    float v = bf2f(vt[((size_t)((b << 5) + h) * 80 + d) * 1024 + blk * 32 + j]) + pos[col];
    F[(size_t)row * 2560 + col] = f2bf(v);
}

// Same but reading row-major bf16 K [token][2560]
__global__ void gatherF_kernel(const u16* __restrict__ src, const float* __restrict__ pos,
                               u16* __restrict__ F)
{
    int row = blockIdx.y;
    int col = blockIdx.x * 256 + threadIdx.x;
    if (col >= 2560) return;
    int b = row >> 10, h = (row >> 5) & 31, blk = row & 31;
    int j = col / 80, d = col - j * 80;
    float v = bf2f(src[(size_t)(b * 1024 + blk * 32 + j) * 2560 + h * 80 + d]) + pos[col];
    F[(size_t)row * 2560 + col] = f2bf(v);
}

// ---------------------------------------------------------------------------
// gates[token][c] = sigmoid(gh . W2[:,c] + b2[c]);  gh bf16, W2/b2 f32
// ---------------------------------------------------------------------------
__global__ __launch_bounds__(256) void gates_kernel(
    const u16* __restrict__ gh, const float* __restrict__ W2,
    const float* __restrict__ b2, float* __restrict__ gates)
{
    int w = threadIdx.x >> 6, lane = threadIdx.x & 63;
    int token = blockIdx.x * 4 + w;
    float s0 = 0.f, s1 = 0.f, s2 = 0.f;
    for (int i = lane; i < 1280; i += 64) {
        float g = bf2f(gh[(size_t)token * 1280 + i]);
        s0 += g * W2[i * 3 + 0];
        s1 += g * W2[i * 3 + 1];
        s2 += g * W2[i * 3 + 2];
    }
#pragma unroll
    for (int m = 1; m < 64; m <<= 1) {
        s0 += __shfl_xor(s0, m);
        s1 += __shfl_xor(s1, m);
        s2 += __shfl_xor(s2, m);
    }
    if (lane == 0) {
        gates[token * 3 + 0] = scrub(1.f / (1.f + expf(-(s0 + b2[0]))));
        gates[token * 3 + 1] = scrub(1.f / (1.f + expf(-(s1 + b2[1]))));
        gates[token * 3 + 2] = scrub(1.f / (1.f + expf(-(s2 + b2[2]))));
    }
}

// ---------------------------------------------------------------------------
// Fused NSA attention: one wave per (bh, 16-query tile).
// qf f32 (accurate); kbf/vt/kc/vc bf16; kmeanS f32 [(b<<5)+blk][2560] = SUM.
// ---------------------------------------------------------------------------
__global__ __launch_bounds__(64) void attn_kernel(
    const float* __restrict__ qf, const u16* __restrict__ kbf,
    const u16* __restrict__ vt, const u16* __restrict__ kc,
    const u16* __restrict__ vc, const float* __restrict__ kmeanS,
    const float* __restrict__ gates, u16* __restrict__ comb)
{
    const int lane = threadIdx.x, quad = lane >> 4, l = lane & 15;
    const int qt = blockIdx.x, bh = blockIdx.y, b = bh >> 5, h = bh & 31;

    __shared__ float bs[16][32];
    __shared__ unsigned int selmask[16];
    __shared__ __align__(16) u16 Pw[16][32];
    __shared__ __align__(16) u16 Ps[16][32];

    const float NEG = -1e30f;

    // ---- block scores in f32 (selection ranking must match np) ----
    {
        const float* qrow = qf + (size_t)(b * 1024 + qt * 16 + l) * 2560 + h * 80;
#pragma unroll
        for (int i = 0; i < 8; i++) {
            int blk = quad * 8 + i;
            const float* km = kmeanS + (size_t)((b << 5) + blk) * 2560 + h * 80;
            float s = 0.f;
            for (int d = 0; d < 80; d += 4) {
                float4 qv = *(const float4*)(qrow + d);
                float4 kv = *(const float4*)(km + d);
                s += qv.x * kv.x + qv.y * kv.y + qv.z * kv.z + qv.w * kv.w;
            }
            bs[l][blk] = s * (SCALE_F * 0.03125f);
        }
    }
    __syncthreads();
    if (lane < 16) {
        unsigned int mask = 0u;
        for (int it = 0; it < 16; it++) {
            float best = NEG; int bi = -1;
            for (int n = 0; n < 32; n++) {
                if (((mask >> n) & 1u) == 0u && bs[lane][n] > best) { best = bs[lane][n]; bi = n; }
            }
            if (bi < 0) { for (int n = 0; n < 32; n++) if (((mask >> n) & 1u) == 0u) { bi = n; break; } }
            mask |= (1u << bi);
        }
        selmask[lane] = mask;
    }
    __syncthreads();
    unsigned int selm[4];
#pragma unroll
    for (int r = 0; r < 4; r++) selm[r] = selmask[quad * 4 + r];

    // ---- Q fragments (A-layout m=lane&15, k=quad*8+j), 80 padded to 96 ----
    v8s qfrag[3];
    {
        const float* qrow = qf + (size_t)(b * 1024 + qt * 16 + l) * 2560 + h * 80;
#pragma unroll
        for (int c = 0; c < 3; c++) {
            union { v8s v; short s[8]; } tmp;
#pragma unroll
            for (int j = 0; j < 8; j++) {
                int hd = c * 32 + quad * 8 + j;
                tmp.s[j] = (short)f2bf(hd < 80 ? qrow[hd] : 0.f);
            }
            qfrag[c] = tmp.v;
        }
    }

    // ---- compressed branch ----
    v4f oc[5];
#pragma unroll
    for (int t = 0; t < 5; t++)
#pragma unroll
        for (int r = 0; r < 4; r++) oc[t][r] = 0.f;
    float l_c[4];
    {
        v4f s0, s1;
#pragma unroll
        for (int r = 0; r < 4; r++) { s0[r] = 0.f; s1[r] = 0.f; }
#pragma unroll
        for (int c = 0; c < 3; c++) {
            v8s b0, b1;
            if (c == 2 && quad >= 2) { b0 = zero8(); b1 = zero8(); }
            else {
                b0 = *(const v8s*)(kc + (size_t)(bh * 32 + l) * 80 + c * 32 + quad * 8);
                b1 = *(const v8s*)(kc + (size_t)(bh * 32 + 16 + l) * 80 + c * 32 + quad * 8);
            }
            s0 = __builtin_amdgcn_mfma_f32_16x16x32_bf16(qfrag[c], b0, s0, 0, 0, 0);
            s1 = __builtin_amdgcn_mfma_f32_16x16x32_bf16(qfrag[c], b1, s1, 0, 0, 0);
        }
#pragma unroll
        for (int r = 0; r < 4; r++) {
            float x0 = s0[r] * SCALE_F, x1 = s1[r] * SCALE_F;
            float mx = fmaxf(x0, x1);
#pragma unroll
            for (int m = 1; m < 16; m <<= 1) mx = fmaxf(mx, __shfl_xor(mx, m));
            float p0 = expf(x0 - mx), p1 = expf(x1 - mx);
            float sm = p0 + p1;
#pragma unroll
            for (int m = 1; m < 16; m <<= 1) sm += __shfl_xor(sm, m);
            l_c[r] = sm;
            Pw[quad * 4 + r][l]      = f2bf(p0);
            Pw[quad * 4 + r][l + 16] = f2bf(p1);
        }
        __syncthreads();
        v8s pa = *(const v8s*)(&Pw[l][quad * 8]);
#pragma unroll
        for (int t = 0; t < 5; t++) {
            union { v8s v; short s[8]; } vf;
#pragma unroll
            for (int j = 0; j < 8; j++)
                vf.s[j] = (short)vc[(size_t)(bh * 32 + quad * 8 + j) * 80 + t * 16 + l];
            oc[t] = __builtin_amdgcn_mfma_f32_16x16x32_bf16(pa, vf.v, oc[t], 0, 0, 0);
        }
        __syncthreads();
    }

    // ---- flash loop: window + selection ----
    v4f aw[5], as_[5];
    float m_w[4], l_w[4], m_s[4], l_s[4];
#pragma unroll
    for (int r = 0; r < 4; r++) { m_w[r] = NEG; l_w[r] = 0.f; m_s[r] = NEG; l_s[r] = 0.f; }
#pragma unroll
    for (int t = 0; t < 5; t++)
#pragma unroll
        for (int r = 0; r < 4; r++) { aw[t][r] = 0.f; as_[t][r] = 0.f; }

    for (int kb = 0; kb < 32; kb++) {
        v4f s0, s1;
#pragma unroll
        for (int r = 0; r < 4; r++) { s0[r] = 0.f; s1[r] = 0.f; }
#pragma unroll
        for (int c = 0; c < 3; c++) {
            v8s k0f, k1f;
            if (c == 2 && quad >= 2) { k0f = zero8(); k1f = zero8(); }
            else {
                size_t base = (size_t)(b * 1024 + kb * 32) * 2560 + h * 80 + c * 32 + quad * 8;
                k0f = *(const v8s*)(kbf + base + (size_t)l * 2560);
                k1f = *(const v8s*)(kbf + base + (size_t)(16 + l) * 2560);
            }
            s0 = __builtin_amdgcn_mfma_f32_16x16x32_bf16(qfrag[c], k0f, s0, 0, 0, 0);
            s1 = __builtin_amdgcn_mfma_f32_16x16x32_bf16(qfrag[c], k1f, s1, 0, 0, 0);
        }
        float alw[4], als[4];
#pragma unroll
        for (int r = 0; r < 4; r++) {
            float x0 = s0[r] * SCALE_F, x1 = s1[r] * SCALE_F;
            float mb = fmaxf(x0, x1);
#pragma unroll
            for (int m = 1; m < 16; m <<= 1) mb = fmaxf(mb, __shfl_xor(mb, m));
            float mn = fmaxf(m_w[r], mb);
            float a  = expf(m_w[r] - mn);
            float p0 = expf(x0 - mn), p1 = expf(x1 - mn);
            float sm = p0 + p1;
#pragma unroll
            for (int m = 1; m < 16; m <<= 1) sm += __shfl_xor(sm, m);
            l_w[r] = l_w[r] * a + sm; m_w[r] = mn; alw[r] = a;
            Pw[quad * 4 + r][l]      = f2bf(p0);
            Pw[quad * 4 + r][l + 16] = f2bf(p1);
            float a2 = 1.f, q0 = 0.f, q1 = 0.f;
            if ((selm[r] >> kb) & 1u) {         // uniform within 16-lane group
                float mn2 = fmaxf(m_s[r], mb);
                a2 = expf(m_s[r] - mn2);
                q0 = expf(x0 - mn2); q1 = expf(x1 - mn2);
                float sm2 = q0 + q1;
#pragma unroll
                for (int m = 1; m < 16; m <<= 1) sm2 += __shfl_xor(sm2, m);
                l_s[r] = l_s[r] * a2 + sm2; m_s[r] = mn2;
            }
            als[r] = a2;
            Ps[quad * 4 + r][l]      = f2bf(q0);
            Ps[quad * 4 + r][l + 16] = f2bf(q1);
        }
        __syncthreads();
        v8s pwa = *(const v8s*)(&Pw[l][quad * 8]);
        v8s psa = *(const v8s*)(&Ps[l][quad * 8]);
#pragma unroll
        for (int t = 0; t < 5; t++) {
            v8s vfr = *(const v8s*)(vt + ((size_t)(bh * 80 + t * 16 + l)) * 1024 + kb * 32 + quad * 8);
#pragma unroll
            for (int r = 0; r < 4; r++) { aw[t][r] *= alw[r]; as_[t][r] *= als[r]; }
            aw[t]  = __builtin_amdgcn_mfma_f32_16x16x32_bf16(pwa, vfr, aw[t], 0, 0, 0);
            as_[t] = __builtin_amdgcn_mfma_f32_16x16x32_bf16(psa, vfr, as_[t], 0, 0, 0);
        }
        __syncthreads();
    }

    // ---- gate-combine + store (bf16 internal) ----
#pragma unroll
    for (int r = 0; r < 4; r++) {
        int token = b * 1024 + qt * 16 + quad * 4 + r;
        float g0 = gates[token * 3 + 0], g1 = gates[token * 3 + 1], g2 = gates[token * 3 + 2];
        float inv_w = 1.f / fmaxf(l_w[r], 1e-30f);
        float inv_s = 1.f / fmaxf(l_s[r], 1e-30f);
        float inv_c = 1.f / fmaxf(l_c[r], 1e-30f);
#pragma unroll
        for (int t = 0; t < 5; t++) {
            float val = g0 * (oc[t][r] * inv_c) + g1 * (as_[t][r] * inv_s) + g2 * (aw[t][r] * inv_w);
            comb[(size_t)token * 2560 + h * 80 + t * 16 + l] = f2bf(scrub(val));
        }
    }
}

// ---------------------------------------------------------------------------
extern "C" void kernel_launch(void* const* d_in, const int* in_sizes, int n_in,
                              void* d_out, int out_size, void* d_ws, size_t ws_size,
                              hipStream_t stream)
{
    (void)in_sizes; (void)n_in; (void)out_size; (void)ws_size;

    // ALL inputs / output are float32 (per reference dtypes).
    const float* X   = (const float*)d_in[0];
    const float* Wq  = (const float*)d_in[1];
    const float* bq  = (const float*)d_in[2];
    const float* Wk  = (const float*)d_in[3];
    const float* bk  = (const float*)d_in[4];
    const float* Wv  = (const float*)d_in[5];
    const float* bv  = (const float*)d_in[6];
    const float* Wo  = (const float*)d_in[7];
    const float* bo  = (const float*)d_in[8];
    const float* pos = (const float*)d_in[9];
    const float* cW1 = (const float*)d_in[10];
    const float* cb1 = (const float*)d_in[11];
    const float* cW2 = (const float*)d_in[12];
    const float* cb2 = (const float*)d_in[13];
    const float* gW1 = (const float*)d_in[14];
    const float* gb1 = (const float*)d_in[15];
    const float* gW2 = (const float*)d_in[16];
    const float* gb2 = (const float*)d_in[17];

    // qf (f32, 20 MB) lives in d_out until the final GEMM overwrites it.
    float* qf = (float*)d_out;

    char* ws = (char*)d_ws;
    size_t off = 0;
    auto alloc = [&](size_t bytes) -> void* {
        void* p = ws + off;
        off += (bytes + 255) & ~(size_t)255;
        return p;
    };
    u16*   kbf    = (u16*)  alloc(2048ull * 2560 * 2);   // 10 MB
    u16*   vtb    = (u16*)  alloc(2048ull * 2560 * 2);   // 10 MB
    // R1: gh -> Fb/H1 -> combb (lifetimes disjoint)
    char*  R1     = (char*) alloc(12ull * 1024 * 1024);
    u16*   gh     = (u16*)R1;
    u16*   Fb     = (u16*)R1;
    u16*   H1     = (u16*)(R1 + 10ull * 1024 * 1024);
    u16*   combb  = (u16*)R1;
    float* kmeanS = (float*)alloc(64ull * 2560 * 4);
    u16*   KC     = (u16*)  alloc(2048ull * 80 * 2);
    u16*   VC     = (u16*)  alloc(2048ull * 80 * 2);
    float* gatesf = (float*)alloc(2048ull * 3 * 4);
    // total ~33.3 MB

    dim3 blk(256);
    hipMemsetAsync(kmeanS, 0, 64ull * 2560 * 4, stream);
    // Q,K: split bf16x3 (~f32 accurate — top-k ranking must match np)
    gemmS_kernel<<<dim3(32, 40), blk, 0, stream>>>(X, Wq, bq, 2048, 2560, 2560, nullptr, qf, nullptr);
    gemmS_kernel<<<dim3(32, 40), blk, 0, stream>>>(X, Wk, bk, 2048, 2560, 2560, kbf, nullptr, kmeanS);
    // V, gate1: plain bf16
    gemm_kernel<<<dim3(32, 40), blk, 0, stream>>>(X, Wv, bv, 2048, 2560, 2560, 0, 1, nullptr, nullptr, vtb);
    gemm_kernel<<<dim3(32, 20), blk, 0, stream>>>(X, gW1, gb1, 2048, 1280, 2560, 1, 1, gh, nullptr, nullptr);
    gates_kernel<<<512, 256, 0, stream>>>(gh, gW2, gb2, gatesf);
    // compression MLP (K then V)
    gatherF_kernel<<<dim3(10, 2048), 256, 0, stream>>>(kbf, pos, Fb);
    gemm_kernel<<<dim3(32, 5), blk, 0, stream>>>(Fb, cW1, cb1, 2048, 320, 2560, 1, 0, H1, nullptr, nullptr);
    gemm_kernel<<<dim3(32, 2), blk, 0, stream>>>(H1, cW2, cb2, 2048, 80, 320, 0, 0, KC, nullptr, nullptr);
    gatherFT_kernel<<<dim3(10, 2048), 256, 0, stream>>>(vtb, pos, Fb);
    gemm_kernel<<<dim3(32, 5), blk, 0, stream>>>(Fb, cW1, cb1, 2048, 320, 2560, 1, 0, H1, nullptr, nullptr);
    gemm_kernel<<<dim3(32, 2), blk, 0, stream>>>(H1, cW2, cb2, 2048, 80, 320, 0, 0, VC, nullptr, nullptr);
    // fused attention -> combb
    attn_kernel<<<dim3(64, 64), 64, 0, stream>>>(qf, kbf, vtb, KC, VC, kmeanS, gatesf, combb);
    // output projection (overwrites qf/d_out)
    gemm_kernel<<<dim3(32, 40), blk, 0, stream>>>(combb, Wo, bo, 2048, 2560, 2560, 0, 0, nullptr, (float*)d_out, nullptr);
}

// Round 4
// 1268.691 us; speedup vs baseline: 1.4180x; 1.4180x over previous
//
#include <hip/hip_runtime.h>
#include <hip/hip_bf16.h>
#include <math.h>

typedef unsigned short u16;
typedef short v8s __attribute__((ext_vector_type(8)));
typedef float v4f __attribute__((ext_vector_type(4)));

#define SCALE_F 0.11180339887498949f

__device__ __forceinline__ float bf2f(u16 x) {
    unsigned int u = ((unsigned int)x) << 16;
    return __builtin_bit_cast(float, u);
}
__device__ __forceinline__ u16 f2bf(float f) {
    unsigned int u = __builtin_bit_cast(unsigned int, f);
    unsigned int r = (u + 0x7FFFu + ((u >> 16) & 1u)) >> 16;
    return (u16)r;
}
__device__ __forceinline__ float scrub(float v) {
    return (fabsf(v) < 1e30f) ? v : 0.f;
}
__device__ __forceinline__ v8s zero8() {
    union { v8s v; short s[8]; } t;
#pragma unroll
    for (int i = 0; i < 8; i++) t.s[i] = 0;
    return t.v;
}

// ---------------------------------------------------------------------------
// convX: f32 -> bf16 elementwise (n % 4 == 0)
// ---------------------------------------------------------------------------
__global__ void convX_kernel(const float* __restrict__ X, u16* __restrict__ Xb, int n)
{
    int i = (blockIdx.x * 256 + threadIdx.x) * 4;
    if (i >= n) return;
    float4 v = *(const float4*)(X + i);
    u16 o[4] = { f2bf(v.x), f2bf(v.y), f2bf(v.z), f2bf(v.w) };
    *(uint2*)(Xb + i) = *(uint2*)o;
}

// ---------------------------------------------------------------------------
// convT: W f32 [K][N] -> WT bf16 [N][K]  (LDS 32x32 tile transpose)
// ---------------------------------------------------------------------------
__global__ __launch_bounds__(256) void convT_kernel(
    const float* __restrict__ W, u16* __restrict__ WT, int K, int N)
{
    __shared__ float t[32][33];
    int n0 = blockIdx.x * 32, k0 = blockIdx.y * 32;
    int tx = threadIdx.x & 31, ty = threadIdx.x >> 5;
    for (int i = ty; i < 32; i += 8) {
        int k = k0 + i, n = n0 + tx;
        t[i][tx] = (k < K && n < N) ? W[(size_t)k * N + n] : 0.f;
    }
    __syncthreads();
    for (int i = ty; i < 32; i += 8) {
        int n = n0 + i, k = k0 + tx;
        if (n < N && k < K) WT[(size_t)n * K + k] = f2bf(t[tx][i]);
    }
}

// ---------------------------------------------------------------------------
// xmean: Xm[g][c] = mean over 32 tokens of X[g*32+j][c]   (g = b*32+blk, 64 rows)
// ---------------------------------------------------------------------------
__global__ void xmean_kernel(const float* __restrict__ X, float* __restrict__ Xm)
{
    int c = blockIdx.x * 256 + threadIdx.x;
    if (c >= 2560) return;
    int g = blockIdx.y;
    const float* base = X + (size_t)g * 32 * 2560 + c;
    float s = 0.f;
#pragma unroll 4
    for (int j = 0; j < 32; j++) s += base[(size_t)j * 2560];
    Xm[(size_t)g * 2560 + c] = s * (1.f / 32.f);
}

// ---------------------------------------------------------------------------
// Split-precision GEMM (bf16x3 ~ f32): C = A[M,K]@B[K,N] + bias. (kmean only)
// ---------------------------------------------------------------------------
__global__ __launch_bounds__(256) void gemmS_kernel(
    const float* __restrict__ A, const float* __restrict__ B,
    const float* __restrict__ bias, int M, int N, int K, float* __restrict__ outf)
{
    __shared__ __align__(16) u16 Ah[64][32], Al[64][32];
    __shared__ __align__(16) u16 Bh[64][32], Bl[64][32];
    const int tid = threadIdx.x;
    const int bm = blockIdx.x * 64, bn = blockIdx.y * 64;
    const int w = tid >> 6, lane = tid & 63;
    const int quad = lane >> 4, l = lane & 15;
    v4f acc[4];
#pragma unroll
    for (int nt = 0; nt < 4; nt++)
#pragma unroll
        for (int r = 0; r < 4; r++) acc[nt][r] = 0.f;
    const int ar = tid >> 2, ak = (tid & 3) * 8;
    const int kr = tid >> 3, nc = (tid & 7) * 8;
    for (int k0 = 0; k0 < K; k0 += 32) {
        float4 a0 = *(const float4*)(A + (size_t)(bm + ar) * K + (k0 + ak));
        float4 a1 = *(const float4*)(A + (size_t)(bm + ar) * K + (k0 + ak) + 4);
        float4 b0 = *(const float4*)(B + (size_t)(k0 + kr) * N + (bn + nc));
        float4 b1 = *(const float4*)(B + (size_t)(k0 + kr) * N + (bn + nc) + 4);
        float av[8] = {a0.x,a0.y,a0.z,a0.w,a1.x,a1.y,a1.z,a1.w};
        float bv[8] = {b0.x,b0.y,b0.z,b0.w,b1.x,b1.y,b1.z,b1.w};
        __syncthreads();
#pragma unroll
        for (int j = 0; j < 8; j++) {
            u16 h = f2bf(av[j]);
            Ah[ar][ak + j] = h; Al[ar][ak + j] = f2bf(av[j] - bf2f(h));
            u16 g = f2bf(bv[j]);
            Bh[nc + j][kr] = g; Bl[nc + j][kr] = f2bf(bv[j] - bf2f(g));
        }
        __syncthreads();
        v8s ah = *(const v8s*)(&Ah[w * 16 + l][quad * 8]);
        v8s al = *(const v8s*)(&Al[w * 16 + l][quad * 8]);
#pragma unroll
        for (int nt = 0; nt < 4; nt++) {
            v8s bh = *(const v8s*)(&Bh[nt * 16 + l][quad * 8]);
            v8s bl = *(const v8s*)(&Bl[nt * 16 + l][quad * 8]);
            acc[nt] = __builtin_amdgcn_mfma_f32_16x16x32_bf16(ah, bh, acc[nt], 0, 0, 0);
            acc[nt] = __builtin_amdgcn_mfma_f32_16x16x32_bf16(ah, bl, acc[nt], 0, 0, 0);
            acc[nt] = __builtin_amdgcn_mfma_f32_16x16x32_bf16(al, bh, acc[nt], 0, 0, 0);
        }
    }
#pragma unroll
    for (int nt = 0; nt < 4; nt++) {
        int col = bn + nt * 16 + l;
        float bvs = bias[col];
#pragma unroll
        for (int r = 0; r < 4; r++) {
            int row = bm + w * 16 + quad * 4 + r;
            outf[(size_t)row * N + col] = scrub(acc[nt][r] + bvs);
        }
    }
}

// ---------------------------------------------------------------------------
// m1: M1T[(b*1024 + h*32+blk)][k] = sum_d Wq[k][h*80+d]*kmean[(b<<5)+blk][h*80+d]
//     written split hi/lo bf16. grid (40 k-tiles, 32 h, 2 b), 256 thr.
// ---------------------------------------------------------------------------
__global__ __launch_bounds__(256) void m1_kernel(
    const float* __restrict__ Wq, const float* __restrict__ km,
    u16* __restrict__ M1hT, u16* __restrict__ M1lT)
{
    __shared__ float Ws[64][81];
    __shared__ float Ks[32][80];
    int k0 = blockIdx.x * 64, h = blockIdx.y, b = blockIdx.z;
    int tid = threadIdx.x;
    for (int i = tid; i < 64 * 80; i += 256) {
        int kk = i / 80, dd = i - kk * 80;
        Ws[kk][dd] = Wq[(size_t)(k0 + kk) * 2560 + h * 80 + dd];
    }
    for (int i = tid; i < 32 * 80; i += 256) {
        int bl = i / 80, dd = i - bl * 80;
        Ks[bl][dd] = km[(size_t)((b << 5) + bl) * 2560 + h * 80 + dd];
    }
    __syncthreads();
    int kk = tid & 63, bq4 = tid >> 6;
    for (int bt = 0; bt < 8; bt++) {
        int blk = bt * 4 + bq4;
        float s = 0.f;
#pragma unroll 8
        for (int d = 0; d < 80; d++) s += Ws[kk][d] * Ks[blk][d];
        u16 hi = f2bf(s);
        size_t o = (size_t)(b * 1024 + h * 32 + blk) * 2560 + k0 + kk;
        M1hT[o] = hi;
        M1lT[o] = f2bf(s - bf2f(hi));
    }
}

// bias3[b*1024+hb] = sum_d bq[h*80+d]*kmean[(b<<5)+blk][h*80+d]
__global__ void bias3_kernel(const float* __restrict__ bq, const float* __restrict__ km,
                             float* __restrict__ bias3)
{
    int i = blockIdx.x * 256 + threadIdx.x;
    if (i >= 2048) return;
    int b = i >> 10, hb = i & 1023, h = hb >> 5, blk = hb & 31;
    float s = 0.f;
    for (int d = 0; d < 80; d++) s += bq[h * 80 + d] * km[(size_t)((b << 5) + blk) * 2560 + h * 80 + d];
    bias3[i] = s;
}

// ---------------------------------------------------------------------------
// gemmS2: BS = A(f32, split inline) @ BT(pre-split bf16 [N][K])^T + bias -> f32
// ---------------------------------------------------------------------------
__global__ __launch_bounds__(256) void gemmS2_kernel(
    const float* __restrict__ A, const u16* __restrict__ BhT, const u16* __restrict__ BlT,
    const float* __restrict__ bias, int M, int N, int K, float* __restrict__ outf)
{
    __shared__ __align__(16) u16 Ah[64][32], Al[64][32];
    __shared__ __align__(16) u16 Bh[64][32], Bl[64][32];
    const int tid = threadIdx.x;
    const int bm = blockIdx.x * 64, bn = blockIdx.y * 64;
    const int w = tid >> 6, lane = tid & 63;
    const int quad = lane >> 4, l = lane & 15;
    v4f acc[4];
#pragma unroll
    for (int nt = 0; nt < 4; nt++)
#pragma unroll
        for (int r = 0; r < 4; r++) acc[nt][r] = 0.f;
    const int ar = tid >> 2, ak = (tid & 3) * 8;
    for (int k0 = 0; k0 < K; k0 += 32) {
        float4 a0 = *(const float4*)(A + (size_t)(bm + ar) * K + (k0 + ak));
        float4 a1 = *(const float4*)(A + (size_t)(bm + ar) * K + (k0 + ak) + 4);
        float av[8] = {a0.x,a0.y,a0.z,a0.w,a1.x,a1.y,a1.z,a1.w};
        uint4 bh8 = *(const uint4*)(BhT + (size_t)(bn + ar) * K + (k0 + ak));
        uint4 bl8 = *(const uint4*)(BlT + (size_t)(bn + ar) * K + (k0 + ak));
        __syncthreads();
#pragma unroll
        for (int j = 0; j < 8; j++) {
            u16 h = f2bf(av[j]);
            Ah[ar][ak + j] = h; Al[ar][ak + j] = f2bf(av[j] - bf2f(h));
        }
        *(uint4*)(&Bh[ar][ak]) = bh8;
        *(uint4*)(&Bl[ar][ak]) = bl8;
        __syncthreads();
        v8s ah = *(const v8s*)(&Ah[w * 16 + l][quad * 8]);
        v8s al = *(const v8s*)(&Al[w * 16 + l][quad * 8]);
#pragma unroll
        for (int nt = 0; nt < 4; nt++) {
            v8s bh = *(const v8s*)(&Bh[nt * 16 + l][quad * 8]);
            v8s bl = *(const v8s*)(&Bl[nt * 16 + l][quad * 8]);
            acc[nt] = __builtin_amdgcn_mfma_f32_16x16x32_bf16(ah, bh, acc[nt], 0, 0, 0);
            acc[nt] = __builtin_amdgcn_mfma_f32_16x16x32_bf16(ah, bl, acc[nt], 0, 0, 0);
            acc[nt] = __builtin_amdgcn_mfma_f32_16x16x32_bf16(al, bh, acc[nt], 0, 0, 0);
        }
    }
#pragma unroll
    for (int nt = 0; nt < 4; nt++) {
        int col = bn + nt * 16 + l;
        float bvs = bias[col];
#pragma unroll
        for (int r = 0; r < 4; r++) {
            int row = bm + w * 16 + quad * 4 + r;
            outf[(size_t)row * N + col] = scrub(acc[nt][r] + bvs);
        }
    }
}

// ---------------------------------------------------------------------------
// gemmB: C = act(A[M,K]@BT[N,K]^T + bias). A (+optional Al split) bf16, BT bf16.
// outb bf16 (ldc), outf f32 (ldc), outT transposed-V bf16 [b*32+h][96][1024].
// ---------------------------------------------------------------------------
__global__ __launch_bounds__(256) void gemmB_kernel(
    const u16* __restrict__ A, const u16* __restrict__ Al2, const u16* __restrict__ BT,
    const float* __restrict__ bias, int M, int N, int K, int act, int ldc,
    u16* __restrict__ outb, float* __restrict__ outf, u16* __restrict__ outT)
{
    __shared__ __align__(16) u16 As[64][32];
    __shared__ __align__(16) u16 As2[64][32];
    __shared__ __align__(16) u16 Bs[64][32];
    const int tid = threadIdx.x;
    const int bm = blockIdx.x * 64, bn = blockIdx.y * 64;
    const int w = tid >> 6, lane = tid & 63;
    const int quad = lane >> 4, l = lane & 15;
    v4f acc[4];
#pragma unroll
    for (int nt = 0; nt < 4; nt++)
#pragma unroll
        for (int r = 0; r < 4; r++) acc[nt][r] = 0.f;
    const int ar = tid >> 2, ak = (tid & 3) * 8;
    for (int k0 = 0; k0 < K; k0 += 32) {
        uint4 av = *(const uint4*)(A + (size_t)(bm + ar) * K + (k0 + ak));
        uint4 av2 = make_uint4(0,0,0,0);
        if (Al2) av2 = *(const uint4*)(Al2 + (size_t)(bm + ar) * K + (k0 + ak));
        uint4 bv = make_uint4(0,0,0,0);
        if (bn + ar < N) bv = *(const uint4*)(BT + (size_t)(bn + ar) * K + (k0 + ak));
        __syncthreads();
        *(uint4*)(&As[ar][ak]) = av;
        if (Al2) *(uint4*)(&As2[ar][ak]) = av2;
        *(uint4*)(&Bs[ar][ak]) = bv;
        __syncthreads();
        v8s af = *(const v8s*)(&As[w * 16 + l][quad * 8]);
#pragma unroll
        for (int nt = 0; nt < 4; nt++) {
            v8s bf = *(const v8s*)(&Bs[nt * 16 + l][quad * 8]);
            acc[nt] = __builtin_amdgcn_mfma_f32_16x16x32_bf16(af, bf, acc[nt], 0, 0, 0);
        }
        if (Al2) {
            v8s af2 = *(const v8s*)(&As2[w * 16 + l][quad * 8]);
#pragma unroll
            for (int nt = 0; nt < 4; nt++) {
                v8s bf = *(const v8s*)(&Bs[nt * 16 + l][quad * 8]);
                acc[nt] = __builtin_amdgcn_mfma_f32_16x16x32_bf16(af2, bf, acc[nt], 0, 0, 0);
            }
        }
    }
#pragma unroll
    for (int nt = 0; nt < 4; nt++) {
        int col = bn + nt * 16 + l;
        if (col < N) {
            float bvs = bias[col];
#pragma unroll
            for (int r = 0; r < 4; r++) {
                int row = bm + w * 16 + quad * 4 + r;
                float c = acc[nt][r] + bvs;
                if (act == 1) c = 0.5f * c * (1.0f + erff(c * 0.70710678118654752f));
                c = scrub(c);
                if (outf) outf[(size_t)row * ldc + col] = c;
                if (outb) outb[(size_t)row * ldc + col] = f2bf(c);
                if (outT) {
                    int bb = row >> 10, s = row & 1023;
                    int hh = col / 80, dd = col - hh * 80;
                    outT[((size_t)((bb << 5) + hh) * 96 + dd) * 1024 + s] = f2bf(c);
                }
            }
        }
    }
}

// padV: vt rows 80..95: row 80 = 1.0, rows 81..95 = 0 (ones-column for row sums)
__global__ void padv_kernel(u16* __restrict__ vt)
{
    int i = blockIdx.x * 256 + threadIdx.x;
    if (i >= 64 * 16 * 1024) return;
    int s = i & 1023, rr = (i >> 10) & 15, bh = i >> 14;
    vt[((size_t)bh * 96 + 80 + rr) * 1024 + s] = (rr == 0) ? (u16)0x3F80 : (u16)0;
}

// ---------------------------------------------------------------------------
// gatherF / gatherFT: compression-MLP input = K/V + comp_pos
// ---------------------------------------------------------------------------
__global__ void gatherF_kernel(const u16* __restrict__ src, const float* __restrict__ pos,
                               u16* __restrict__ F)
{
    int row = blockIdx.y;
    int col = blockIdx.x * 256 + threadIdx.x;
    if (col >= 2560) return;
    int b = row >> 10, h = (row >> 5) & 31, blk = row & 31;
    int j = col / 80, d = col - j * 80;
    float v = bf2f(src[(size_t)(b * 1024 + blk * 32 + j) * 2560 + h * 80 + d]) + pos[col];
    F[(size_t)row * 2560 + col] = f2bf(v);
}
__global__ void gatherFT_kernel(const u16* __restrict__ vt, const float* __restrict__ pos,
                                u16* __restrict__ F)
{
    int row = blockIdx.y;
    int col = blockIdx.x * 256 + threadIdx.x;
    if (col >= 2560) return;
    int b = row >> 10, h = (row >> 5) & 31, blk = row & 31;
    int j = col / 80, d = col - j * 80;
    float v = bf2f(vt[((size_t)((b << 5) + h) * 96 + d) * 1024 + blk * 32 + j]) + pos[col];
    F[(size_t)row * 2560 + col] = f2bf(v);
}

// ---------------------------------------------------------------------------
// gates
// ---------------------------------------------------------------------------
__global__ __launch_bounds__(256) void gates_kernel(
    const u16* __restrict__ gh, const float* __restrict__ W2,
    const float* __restrict__ b2, float* __restrict__ gates)
{
    int w = threadIdx.x >> 6, lane = threadIdx.x & 63;
    int token = blockIdx.x * 4 + w;
    float s0 = 0.f, s1 = 0.f, s2 = 0.f;
    for (int i = lane; i < 1280; i += 64) {
        float g = bf2f(gh[(size_t)token * 1280 + i]);
        s0 += g * W2[i * 3 + 0];
        s1 += g * W2[i * 3 + 1];
        s2 += g * W2[i * 3 + 2];
    }
#pragma unroll
    for (int m = 1; m < 64; m <<= 1) {
        s0 += __shfl_xor(s0, m);
        s1 += __shfl_xor(s1, m);
        s2 += __shfl_xor(s2, m);
    }
    if (lane == 0) {
        gates[token * 3 + 0] = scrub(1.f / (1.f + expf(-(s0 + b2[0]))));
        gates[token * 3 + 1] = scrub(1.f / (1.f + expf(-(s1 + b2[1]))));
        gates[token * 3 + 2] = scrub(1.f / (1.f + expf(-(s2 + b2[2]))));
    }
}

// ---------------------------------------------------------------------------
// Fused NSA attention v2: one wave per (bh, 16-query tile).
// qb bf16; kbf bf16; vt bf16 [bh][96][1024] (row 80 = ones); kc/vc bf16;
// BSf f32 [b][1024 tok][1024 (h,blk)]; outputs comb hi/lo bf16.
// Selection branch shares the window softmax stabilizer (shift-invariant) and
// uses a per-lane-masked P fragment; row sums via ones-column V tile (t=5).
// ---------------------------------------------------------------------------
__global__ __launch_bounds__(64) void attn_kernel(
    const u16* __restrict__ qb, const u16* __restrict__ kbf,
    const u16* __restrict__ vt, const u16* __restrict__ kc,
    const u16* __restrict__ vc, const float* __restrict__ BSf,
    const float* __restrict__ gates, u16* __restrict__ comb, u16* __restrict__ combl)
{
    const int lane = threadIdx.x, quad = lane >> 4, l = lane & 15;
    const int qt = blockIdx.x, bh = blockIdx.y, b = bh >> 5, h = bh & 31;
    const float NEG = -1e30f;

    __shared__ float bs[16][33];
    __shared__ unsigned int selmask[16];
    __shared__ __align__(16) u16 Pw[16][40];

    // ---- block scores from precomputed BS (f32-accurate) ----
    {
        const float* bsrow = BSf + ((size_t)b * 1024 + qt * 16 + l) * 1024 + h * 32 + quad * 8;
#pragma unroll
        for (int i = 0; i < 8; i++) bs[l][quad * 8 + i] = bsrow[i] * SCALE_F;
    }
    __syncthreads();
    if (lane < 16) {
        unsigned int mask = 0u;
        for (int it = 0; it < 16; it++) {
            float best = NEG; int bi = -1;
            for (int n = 0; n < 32; n++) {
                if (((mask >> n) & 1u) == 0u && bs[lane][n] > best) { best = bs[lane][n]; bi = n; }
            }
            if (bi < 0) { for (int n = 0; n < 32; n++) if (((mask >> n) & 1u) == 0u) { bi = n; break; } }
            mask |= (1u << bi);
        }
        selmask[lane] = mask;
    }
    __syncthreads();
    const unsigned int selm_l = selmask[l];   // mask for THIS lane's A-row (query l)
    unsigned int selm[4];
#pragma unroll
    for (int r = 0; r < 4; r++) selm[r] = selmask[quad * 4 + r];  // for epilogue sanity (unused mask path)
    (void)selm;

    // ---- Q fragments (A-layout m=lane&15, k=quad*8+j), 80 padded to 96 ----
    v8s qfrag[3];
    {
        const u16* qrow = qb + (size_t)(b * 1024 + qt * 16 + l) * 2560 + h * 80;
#pragma unroll
        for (int c = 0; c < 3; c++) {
            if (c == 2 && quad >= 2) { qfrag[c] = zero8(); }
            else qfrag[c] = *(const v8s*)(qrow + c * 32 + quad * 8);
        }
    }

    // ---- compressed branch (runs once; shuffle sums kept) ----
    v4f oc[5];
#pragma unroll
    for (int t = 0; t < 5; t++)
#pragma unroll
        for (int r = 0; r < 4; r++) oc[t][r] = 0.f;
    float l_c[4];
    {
        v4f s0, s1;
#pragma unroll
        for (int r = 0; r < 4; r++) { s0[r] = 0.f; s1[r] = 0.f; }
#pragma unroll
        for (int c = 0; c < 3; c++) {
            v8s b0, b1;
            if (c == 2 && quad >= 2) { b0 = zero8(); b1 = zero8(); }
            else {
                b0 = *(const v8s*)(kc + (size_t)(bh * 32 + l) * 80 + c * 32 + quad * 8);
                b1 = *(const v8s*)(kc + (size_t)(bh * 32 + 16 + l) * 80 + c * 32 + quad * 8);
            }
            s0 = __builtin_amdgcn_mfma_f32_16x16x32_bf16(qfrag[c], b0, s0, 0, 0, 0);
            s1 = __builtin_amdgcn_mfma_f32_16x16x32_bf16(qfrag[c], b1, s1, 0, 0, 0);
        }
#pragma unroll
        for (int r = 0; r < 4; r++) {
            float x0 = s0[r] * SCALE_F, x1 = s1[r] * SCALE_F;
            float mx = fmaxf(x0, x1);
#pragma unroll
            for (int m = 1; m < 16; m <<= 1) mx = fmaxf(mx, __shfl_xor(mx, m));
            float p0 = expf(x0 - mx), p1 = expf(x1 - mx);
            float sm = p0 + p1;
#pragma unroll
            for (int m = 1; m < 16; m <<= 1) sm += __shfl_xor(sm, m);
            l_c[r] = sm;
            Pw[quad * 4 + r][l]      = f2bf(p0);
            Pw[quad * 4 + r][l + 16] = f2bf(p1);
        }
        __syncthreads();
        v8s pa = *(const v8s*)(&Pw[l][quad * 8]);
#pragma unroll
        for (int t = 0; t < 5; t++) {
            union { v8s v; short s[8]; } vf;
#pragma unroll
            for (int j = 0; j < 8; j++)
                vf.s[j] = (short)vc[(size_t)(bh * 32 + quad * 8 + j) * 80 + t * 16 + l];
            oc[t] = __builtin_amdgcn_mfma_f32_16x16x32_bf16(pa, vf.v, oc[t], 0, 0, 0);
        }
        __syncthreads();
    }

    // ---- flash loop: window + selection (shared stabilizer) ----
    v4f aw[6], as_[6];
    float m_w[4];
#pragma unroll
    for (int r = 0; r < 4; r++) m_w[r] = NEG;
#pragma unroll
    for (int t = 0; t < 6; t++)
#pragma unroll
        for (int r = 0; r < 4; r++) { aw[t][r] = 0.f; as_[t][r] = 0.f; }

    const u16* vtp = vt + (size_t)bh * 96 * 1024;

    for (int kb = 0; kb < 32; kb++) {
        v4f s0, s1;
#pragma unroll
        for (int r = 0; r < 4; r++) { s0[r] = 0.f; s1[r] = 0.f; }
#pragma unroll
        for (int c = 0; c < 3; c++) {
            v8s k0f, k1f;
            if (c == 2 && quad >= 2) { k0f = zero8(); k1f = zero8(); }
            else {
                size_t base = (size_t)(b * 1024 + kb * 32) * 2560 + h * 80 + c * 32 + quad * 8;
                k0f = *(const v8s*)(kbf + base + (size_t)l * 2560);
                k1f = *(const v8s*)(kbf + base + (size_t)(16 + l) * 2560);
            }
            s0 = __builtin_amdgcn_mfma_f32_16x16x32_bf16(qfrag[c], k0f, s0, 0, 0, 0);
            s1 = __builtin_amdgcn_mfma_f32_16x16x32_bf16(qfrag[c], k1f, s1, 0, 0, 0);
        }
        float alw[4];
#pragma unroll
        for (int r = 0; r < 4; r++) {
            float x0 = s0[r] * SCALE_F, x1 = s1[r] * SCALE_F;
            float mb = fmaxf(x0, x1);
#pragma unroll
            for (int m = 1; m < 16; m <<= 1) mb = fmaxf(mb, __shfl_xor(mb, m));
            float mn = fmaxf(m_w[r], mb);
            alw[r] = expf(m_w[r] - mn);
            m_w[r] = mn;
            Pw[quad * 4 + r][l]      = f2bf(expf(x0 - mn));
            Pw[quad * 4 + r][l + 16] = f2bf(expf(x1 - mn));
        }
        __syncthreads();
        v8s pwa = *(const v8s*)(&Pw[l][quad * 8]);
        v8s psa = ((selm_l >> kb) & 1u) ? pwa : zero8();
#pragma unroll
        for (int t = 0; t < 6; t++) {
            v8s vfr = *(const v8s*)(vtp + ((size_t)(t * 16 + l)) * 1024 + kb * 32 + quad * 8);
#pragma unroll
            for (int r = 0; r < 4; r++) { aw[t][r] *= alw[r]; as_[t][r] *= alw[r]; }
            aw[t]  = __builtin_amdgcn_mfma_f32_16x16x32_bf16(pwa, vfr, aw[t], 0, 0, 0);
            as_[t] = __builtin_amdgcn_mfma_f32_16x16x32_bf16(psa, vfr, as_[t], 0, 0, 0);
        }
        __syncthreads();
    }

    // ---- row sums from ones-column tile (t=5, col 0 held at lane quad*16) ----
    float l_w[4], l_s[4];
#pragma unroll
    for (int r = 0; r < 4; r++) {
        l_w[r] = __shfl(aw[5][r], quad * 16);
        l_s[r] = __shfl(as_[5][r], quad * 16);
    }

    // ---- gate-combine + split store ----
#pragma unroll
    for (int r = 0; r < 4; r++) {
        int token = b * 1024 + qt * 16 + quad * 4 + r;
        float g0 = gates[token * 3 + 0], g1 = gates[token * 3 + 1], g2 = gates[token * 3 + 2];
        float inv_w = 1.f / fmaxf(l_w[r], 1e-30f);
        float inv_s = 1.f / fmaxf(l_s[r], 1e-30f);
        float inv_c = 1.f / fmaxf(l_c[r], 1e-30f);
#pragma unroll
        for (int t = 0; t < 5; t++) {
            float val = g0 * (oc[t][r] * inv_c) + g1 * (as_[t][r] * inv_s) + g2 * (aw[t][r] * inv_w);
            val = scrub(val);
            u16 hi = f2bf(val);
            size_t o = (size_t)token * 2560 + h * 80 + t * 16 + l;
            comb[o] = hi;
            combl[o] = f2bf(val - bf2f(hi));
        }
    }
}

// ---------------------------------------------------------------------------
extern "C" void kernel_launch(void* const* d_in, const int* in_sizes, int n_in,
                              void* d_out, int out_size, void* d_ws, size_t ws_size,
                              hipStream_t stream)
{
    (void)in_sizes; (void)n_in; (void)out_size; (void)ws_size;

    const float* X   = (const float*)d_in[0];
    const float* Wq  = (const float*)d_in[1];
    const float* bq  = (const float*)d_in[2];
    const float* Wk  = (const float*)d_in[3];
    const float* bk  = (const float*)d_in[4];
    const float* Wv  = (const float*)d_in[5];
    const float* bv  = (const float*)d_in[6];
    const float* Wo  = (const float*)d_in[7];
    const float* bo  = (const float*)d_in[8];
    const float* pos = (const float*)d_in[9];
    const float* cW1 = (const float*)d_in[10];
    const float* cb1 = (const float*)d_in[11];
    const float* cW2 = (const float*)d_in[12];
    const float* cb2 = (const float*)d_in[13];
    const float* gW1 = (const float*)d_in[14];
    const float* gb1 = (const float*)d_in[15];
    const float* gW2 = (const float*)d_in[16];
    const float* gb2 = (const float*)d_in[17];

    char* ws = (char*)d_ws;
    size_t off = 0;
    auto alloc = [&](size_t bytes) -> void* {
        void* p = ws + off;
        off += (bytes + 255) & ~(size_t)255;
        return p;
    };
    u16*   Xb     = (u16*)  alloc(2048ull * 2560 * 2);       // 10.5 MB
    u16*   WqT    = (u16*)  alloc(2560ull * 2560 * 2);       // 13.1
    u16*   WkT    = (u16*)  alloc(2560ull * 2560 * 2);
    u16*   WvT    = (u16*)  alloc(2560ull * 2560 * 2);
    u16*   WoT    = (u16*)  alloc(2560ull * 2560 * 2);
    u16*   gW1T   = (u16*)  alloc(1280ull * 2560 * 2);       // 6.6
    u16*   cW1T   = (u16*)  alloc(320ull * 2560 * 2);        // 1.6
    u16*   cW2T   = (u16*)  alloc(96ull * 320 * 2);
    float* Xm     = (float*)alloc(64ull * 2560 * 4);
    float* kmeanS = (float*)alloc(64ull * 2560 * 4);
    u16*   M1hT   = (u16*)  alloc(2048ull * 2560 * 2);       // 10.5
    u16*   M1lT   = (u16*)  alloc(2048ull * 2560 * 2);       // 10.5
    float* bias3  = (float*)alloc(2048ull * 4);
    u16*   qbuf   = (u16*)  alloc(2048ull * 2560 * 2);       // 10.5
    u16*   kbf    = (u16*)  alloc(2048ull * 2560 * 2);       // 10.5
    u16*   vtb    = (u16*)  alloc(64ull * 96 * 1024 * 2);    // 12.6
    u16*   combl  = (u16*)  alloc(2048ull * 2560 * 2);       // 10.5
    char*  R1     = (char*) alloc(12ull * 1024 * 1024);      // gh -> Fb/H1 -> combb
    u16*   gh     = (u16*)R1;
    u16*   Fb     = (u16*)R1;
    u16*   H1     = (u16*)(R1 + 10ull * 1024 * 1024);
    u16*   combb  = (u16*)R1;
    u16*   KC     = (u16*)  alloc(2048ull * 80 * 2);
    u16*   VC     = (u16*)  alloc(2048ull * 80 * 2);
    float* gatesf = (float*)alloc(2048ull * 3 * 4);
    float* BSf    = (float*)d_out;   // 8.4 MB, dead before final GEMM writes d_out

    dim3 blk(256);
    // ---- conversions / transposes ----
    convX_kernel<<<2048 * 2560 / 4 / 256, blk, 0, stream>>>(X, Xb, 2048 * 2560);
    convT_kernel<<<dim3(80, 80), blk, 0, stream>>>(Wq, WqT, 2560, 2560);
    convT_kernel<<<dim3(80, 80), blk, 0, stream>>>(Wk, WkT, 2560, 2560);
    convT_kernel<<<dim3(80, 80), blk, 0, stream>>>(Wv, WvT, 2560, 2560);
    convT_kernel<<<dim3(80, 80), blk, 0, stream>>>(Wo, WoT, 2560, 2560);
    convT_kernel<<<dim3(40, 80), blk, 0, stream>>>(gW1, gW1T, 2560, 1280);
    convT_kernel<<<dim3(10, 80), blk, 0, stream>>>(cW1, cW1T, 2560, 320);
    convT_kernel<<<dim3(3, 10), blk, 0, stream>>>(cW2, cW2T, 320, 80);
    // ---- selection-score pipeline (f32-accurate) ----
    xmean_kernel<<<dim3(10, 64), blk, 0, stream>>>(X, Xm);
    gemmS_kernel<<<dim3(1, 40), blk, 0, stream>>>(Xm, Wk, bk, 64, 2560, 2560, kmeanS);
    m1_kernel<<<dim3(40, 32, 2), blk, 0, stream>>>(Wq, kmeanS, M1hT, M1lT);
    bias3_kernel<<<8, blk, 0, stream>>>(bq, kmeanS, bias3);
    for (int b = 0; b < 2; b++) {
        gemmS2_kernel<<<dim3(16, 16), blk, 0, stream>>>(
            X + (size_t)b * 1024 * 2560, M1hT + (size_t)b * 1024 * 2560,
            M1lT + (size_t)b * 1024 * 2560, bias3 + b * 1024,
            1024, 1024, 2560, BSf + (size_t)b * 1024 * 1024);
    }
    // ---- projections (plain bf16) ----
    gemmB_kernel<<<dim3(32, 40), blk, 0, stream>>>(Xb, nullptr, WqT, bq, 2048, 2560, 2560, 0, 2560, qbuf, nullptr, nullptr);
    gemmB_kernel<<<dim3(32, 40), blk, 0, stream>>>(Xb, nullptr, WkT, bk, 2048, 2560, 2560, 0, 2560, kbf, nullptr, nullptr);
    gemmB_kernel<<<dim3(32, 40), blk, 0, stream>>>(Xb, nullptr, WvT, bv, 2048, 2560, 2560, 0, 2560, nullptr, nullptr, vtb);
    padv_kernel<<<4096, blk, 0, stream>>>(vtb);
    gemmB_kernel<<<dim3(32, 20), blk, 0, stream>>>(Xb, nullptr, gW1T, gb1, 2048, 1280, 2560, 1, 1280, gh, nullptr, nullptr);
    gates_kernel<<<512, blk, 0, stream>>>(gh, gW2, gb2, gatesf);
    // ---- compression MLP (K then V); Fb reuses R1 after gates done ----
    gatherF_kernel<<<dim3(10, 2048), blk, 0, stream>>>(kbf, pos, Fb);
    gemmB_kernel<<<dim3(32, 5), blk, 0, stream>>>(Fb, nullptr, cW1T, cb1, 2048, 320, 2560, 1, 320, H1, nullptr, nullptr);
    gemmB_kernel<<<dim3(32, 2), blk, 0, stream>>>(H1, nullptr, cW2T, cb2, 2048, 80, 320, 0, 80, KC, nullptr, nullptr);
    gatherFT_kernel<<<dim3(10, 2048), blk, 0, stream>>>(vtb, pos, Fb);
    gemmB_kernel<<<dim3(32, 5), blk, 0, stream>>>(Fb, nullptr, cW1T, cb1, 2048, 320, 2560, 1, 320, H1, nullptr, nullptr);
    gemmB_kernel<<<dim3(32, 2), blk, 0, stream>>>(H1, nullptr, cW2T, cb2, 2048, 80, 320, 0, 80, VC, nullptr, nullptr);
    // ---- fused attention -> comb (hi/lo) ----
    attn_kernel<<<dim3(64, 64), 64, 0, stream>>>(qbuf, kbf, vtb, KC, VC, BSf, gatesf, combb, combl);
    // ---- output projection (split-A for margin) ----
    gemmB_kernel<<<dim3(32, 40), blk, 0, stream>>>(combb, combl, WoT, bo, 2048, 2560, 2560, 0, 2560, nullptr, (float*)d_out, nullptr);
}